// Round 4
// baseline (90.036 us; speedup 1.0000x reference)
//
#include <hip/hip_runtime.h>
#include <hip/hip_cooperative_groups.h>
#include <math.h>

namespace cg = cooperative_groups;

#define NV 8
#define NBINS 128
#define GRID_F 128
#define BLK_F 512
#define NWAVE_F (BLK_F / 64)
#define NTH (GRID_F * BLK_F)   // 65536 threads; even -> quad parity fixed per thread

// Partials in our own device globals (not harness-poisoned ws).
__device__ float g_pmin[GRID_F][NV];
__device__ float g_pmax[GRID_F][NV];

// Per-quad processing: 4 consecutive elements = 4 consecutive columns
// (quad parity fixed). Exact reference bin rule preserved:
// candidate via rstep, then monotone fix-up against rint((lin_b - feat)*1e6).
__device__ __forceinline__ void proc4(float4 fvq, int q, const float* __restrict__ slin,
                                      const float* __restrict__ sfmin,
                                      const float* __restrict__ sstep,
                                      const float* __restrict__ srstep,
                                      float* __restrict__ out, int n) {
    const int v0 = (q << 2) & 7;  // 0 or 4
    const int i0 = q << 2;
    float fe[4] = {fvq.x, fvq.y, fvq.z, fvq.w};
    float bins[4], regs[4];
#pragma unroll
    for (int j = 0; j < 4; ++j) {
        const int v = v0 + j;
        const float* lv = &slin[v * 129];
        const float feat = fe[j];
        const float fmn = sfmin[v];
        const float step = sstep[v];
        const float rstep = srstep[v];
        int b = (int)floorf(__fmul_rn(__fsub_rn(feat, fmn), rstep));
        b = b < 0 ? 0 : (b > 127 ? 127 : b);
        while (b < NBINS - 1 &&
               rintf(__fmul_rn(__fsub_rn(lv[b + 1], feat), 1.0e6f)) <= 0.0f) ++b;
        while (b > 0 &&
               rintf(__fmul_rn(__fsub_rn(lv[b], feat), 1.0e6f)) > 0.0f) --b;
        const float val = lv[b];
        bins[j] = (float)b;
        regs[j] = __fdiv_rn(fmaxf(__fsub_rn(feat, val), 0.0f), step);
    }
    *(float4*)(out + i0) = make_float4(bins[0], bins[1], bins[2], bins[3]);
    if ((n & 3) == 0) {  // out+n is 16B-aligned iff n%4==0
        *(float4*)(out + n + i0) = make_float4(regs[0], regs[1], regs[2], regs[3]);
    } else {
        out[n + i0 + 0] = regs[0]; out[n + i0 + 1] = regs[1];
        out[n + i0 + 2] = regs[2]; out[n + i0 + 3] = regs[3];
    }
}

__global__ __launch_bounds__(BLK_F) void k_all(const float* __restrict__ feats,
                                               float* __restrict__ out, int n) {
    const int tid = threadIdx.x;
    const int bid = blockIdx.x;
    const int gid = bid * BLK_F + tid;
    const int wave = tid >> 6, lane = tid & 63;
    const int n4 = n >> 2;
    const float4* f4 = (const float4*)feats;

    // ---- phase 1a: load this thread's quads ONCE; keep in registers ----
    // n4 = 200000 -> threads hold 3 quads (first 3392 hold 4). Extras loop is
    // generic safety for n > 4*NTH*4 elements (empty here).
    const int q0 = gid, q1 = gid + NTH, q2 = gid + 2 * NTH, q3 = gid + 3 * NTH;
    const bool h0 = q0 < n4, h1 = q1 < n4, h2 = q2 < n4, h3 = q3 < n4;
    float4 fv0, fv1, fv2, fv3;
    if (h0) fv0 = f4[q0];
    if (h1) fv1 = f4[q1];
    if (h2) fv2 = f4[q2];
    if (h3) fv3 = f4[q3];

    float lmin[NV], lmax[NV];
#pragma unroll
    for (int c = 0; c < NV; ++c) { lmin[c] = __builtin_inff(); lmax[c] = -__builtin_inff(); }

#define MMA(v, B)                                                            \
    do {                                                                     \
        lmin[B + 0] = fminf(lmin[B + 0], (v).x); lmax[B + 0] = fmaxf(lmax[B + 0], (v).x); \
        lmin[B + 1] = fminf(lmin[B + 1], (v).y); lmax[B + 1] = fmaxf(lmax[B + 1], (v).y); \
        lmin[B + 2] = fminf(lmin[B + 2], (v).z); lmax[B + 2] = fmaxf(lmax[B + 2], (v).z); \
        lmin[B + 3] = fminf(lmin[B + 3], (v).w); lmax[B + 3] = fmaxf(lmax[B + 3], (v).w); \
    } while (0)

    // NTH even -> all of this thread's quads share parity -> one column group
    if (((gid << 2) & 7) == 0) {
        if (h0) MMA(fv0, 0);
        if (h1) MMA(fv1, 0);
        if (h2) MMA(fv2, 0);
        if (h3) MMA(fv3, 0);
        for (int q = gid + 4 * NTH; q < n4; q += NTH) { float4 v = f4[q]; MMA(v, 0); }
    } else {
        if (h0) MMA(fv0, 4);
        if (h1) MMA(fv1, 4);
        if (h2) MMA(fv2, 4);
        if (h3) MMA(fv3, 4);
        for (int q = gid + 4 * NTH; q < n4; q += NTH) { float4 v = f4[q]; MMA(v, 4); }
    }
#undef MMA

    // generic scalar tail (n % 4 != 0) — static-index via unrolled predicate
    for (int i = (n4 << 2) + gid; i < n; i += NTH) {
        float v = feats[i];
        int c = i & 7;
#pragma unroll
        for (int cc = 0; cc < NV; ++cc)
            if (cc == c) { lmin[cc] = fminf(lmin[cc], v); lmax[cc] = fmaxf(lmax[cc], v); }
    }

    // 64-lane wave butterfly per column
#pragma unroll
    for (int c = 0; c < NV; ++c) {
        float mn = lmin[c], mx = lmax[c];
#pragma unroll
        for (int m = 32; m >= 1; m >>= 1) {
            mn = fminf(mn, __shfl_xor(mn, m));
            mx = fmaxf(mx, __shfl_xor(mx, m));
        }
        lmin[c] = mn; lmax[c] = mx;
    }
    __shared__ float smin[NWAVE_F][NV], smax[NWAVE_F][NV];
    if (lane == 0) {
#pragma unroll
        for (int c = 0; c < NV; ++c) { smin[wave][c] = lmin[c]; smax[wave][c] = lmax[c]; }
    }
    __syncthreads();
    if (tid < NV) {
        float mn = __builtin_inff(), mx = -__builtin_inff();
#pragma unroll
        for (int w = 0; w < NWAVE_F; ++w) {
            mn = fminf(mn, smin[w][tid]);
            mx = fmaxf(mx, smax[w][tid]);
        }
        // agent-scope stores to the coherence point (R1-verified visibility path)
        __hip_atomic_store(&g_pmin[bid][tid], mn, __ATOMIC_RELAXED, __HIP_MEMORY_SCOPE_AGENT);
        __hip_atomic_store(&g_pmax[bid][tid], mx, __ATOMIC_RELAXED, __HIP_MEMORY_SCOPE_AGENT);
    }
    __syncthreads();

    // ---- grid-wide sync: ROCm-implemented cooperative barrier ----
    cg::this_grid().sync();

    // ---- phase 2a: one wave combines the 128 partials (2 per lane) ----
    __shared__ float sgmin[NV], sgmax[NV];
    if (tid < 64) {
        float mn[NV], mx[NV];
#pragma unroll
        for (int c = 0; c < NV; ++c) {
            float a0 = __hip_atomic_load(&g_pmin[tid][c],      __ATOMIC_RELAXED, __HIP_MEMORY_SCOPE_AGENT);
            float a1 = __hip_atomic_load(&g_pmin[tid + 64][c], __ATOMIC_RELAXED, __HIP_MEMORY_SCOPE_AGENT);
            float b0 = __hip_atomic_load(&g_pmax[tid][c],      __ATOMIC_RELAXED, __HIP_MEMORY_SCOPE_AGENT);
            float b1 = __hip_atomic_load(&g_pmax[tid + 64][c], __ATOMIC_RELAXED, __HIP_MEMORY_SCOPE_AGENT);
            mn[c] = fminf(a0, a1);
            mx[c] = fmaxf(b0, b1);
        }
#pragma unroll
        for (int c = 0; c < NV; ++c) {
#pragma unroll
            for (int m = 32; m >= 1; m >>= 1) {
                mn[c] = fminf(mn[c], __shfl_xor(mn[c], m));
                mx[c] = fmaxf(mx[c], __shfl_xor(mx[c], m));
            }
        }
        if (tid == 0) {
#pragma unroll
            for (int c = 0; c < NV; ++c) { sgmin[c] = mn[c]; sgmax[c] = mx[c]; }
        }
    }
    __syncthreads();

    // ---- phase 2b: lin table (exact reference arithmetic: mul then add, no FMA) ----
    __shared__ float slin[NV * 129];  // +1 pad: bank = (129v+b)%32 = (v+b)%32
    __shared__ float sfmin[NV], sstep[NV], srstep[NV];
    for (int e = tid; e < NV * NBINS; e += BLK_F) {
        int v = e >> 7;
        int b = e & 127;
        float fmn = sgmin[v];
        float range = __fsub_rn(sgmax[v], fmn);        // (fmax - fmin), f32
        float tb = __fdiv_rn((float)b, 127.0f);        // t[b] = b/127, f32
        slin[v * 129 + b] = __fadd_rn(fmn, __fmul_rn(range, tb));
    }
    __syncthreads();
    if (tid < NV) {
        float s0 = slin[tid * 129 + 0];
        float s1 = slin[tid * 129 + 1];
        sfmin[tid] = s0;
        float st = __fsub_rn(s1, s0);
        sstep[tid] = st;
        srstep[tid] = __fdiv_rn(1.0f, st);  // candidate-only; fixups make bin exact
    }
    __syncthreads();

    // ---- phase 2c: quantize the register-held quads (no feats re-read) ----
    if (h0) proc4(fv0, q0, slin, sfmin, sstep, srstep, out, n);
    if (h1) proc4(fv1, q1, slin, sfmin, sstep, srstep, out, n);
    if (h2) proc4(fv2, q2, slin, sfmin, sstep, srstep, out, n);
    if (h3) proc4(fv3, q3, slin, sfmin, sstep, srstep, out, n);
    for (int q = gid + 4 * NTH; q < n4; q += NTH)
        proc4(f4[q], q, slin, sfmin, sstep, srstep, out, n);

    // scalar tail (n % 4 != 0)
    for (int i = (n4 << 2) + gid; i < n; i += NTH) {
        const int v = i & 7;
        const float feat = feats[i];
        const float* lv = &slin[v * 129];
        const float fmn = sfmin[v];
        const float step = sstep[v];
        int b = (int)floorf(__fmul_rn(__fsub_rn(feat, fmn), srstep[v]));
        b = b < 0 ? 0 : (b > 127 ? 127 : b);
        while (b < NBINS - 1 &&
               rintf(__fmul_rn(__fsub_rn(lv[b + 1], feat), 1.0e6f)) <= 0.0f) ++b;
        while (b > 0 &&
               rintf(__fmul_rn(__fsub_rn(lv[b], feat), 1.0e6f)) > 0.0f) --b;
        out[i] = (float)b;
        out[n + i] = __fdiv_rn(fmaxf(__fsub_rn(feat, lv[b]), 0.0f), step);
    }
}

extern "C" void kernel_launch(void* const* d_in, const int* in_sizes, int n_in,
                              void* d_out, int out_size, void* d_ws, size_t ws_size,
                              hipStream_t stream) {
    const float* feats = (const float*)d_in[0];
    float* out = (float*)d_out;
    int n = in_sizes[0];  // 100000 * 8 flat
    (void)d_ws; (void)ws_size;
    void* args[] = {(void*)&feats, (void*)&out, (void*)&n};
    hipLaunchCooperativeKernel((const void*)k_all, dim3(GRID_F), dim3(BLK_F),
                               args, 0, stream);
}

// Round 5
// 66.260 us; speedup vs baseline: 1.3588x; 1.3588x over previous
//
#include <hip/hip_runtime.h>
#include <math.h>

#define NV 8
#define NBINS 128
#define GRID_A 256
#define BLK_A 256
#define NTH_A (GRID_A * BLK_A)   // 65536; even -> quad parity fixed per thread
#define BLK_Q 256

// ws layout (floats): pmin[256][8] at [0,2048), pmax[256][8] at [2048,4096).
// Every k_colminmax block writes its full row before k_quantize2 reads -> no
// dependence on the harness poison value.

__global__ __launch_bounds__(BLK_A) void k_colminmax(const float* __restrict__ feats,
                                                     float* __restrict__ ws, int n) {
    const int tid = threadIdx.x;
    const int bid = blockIdx.x;
    const int gid = bid * BLK_A + tid;
    const int n4 = n >> 2;
    const float4* f4 = (const float4*)feats;

    // Issue ALL of this thread's quad loads upfront: one HBM latency round.
    // 4 * NTH_A quads = 262144 covers n4 = 200000; safety loop below is generic.
    const int q0 = gid, q1 = gid + NTH_A, q2 = gid + 2 * NTH_A, q3 = gid + 3 * NTH_A;
    const bool h0 = q0 < n4, h1 = q1 < n4, h2 = q2 < n4, h3 = q3 < n4;
    float4 fv0, fv1, fv2, fv3;
    if (h0) fv0 = f4[q0];
    if (h1) fv1 = f4[q1];
    if (h2) fv2 = f4[q2];
    if (h3) fv3 = f4[q3];

    float lmin[NV], lmax[NV];
#pragma unroll
    for (int c = 0; c < NV; ++c) { lmin[c] = __builtin_inff(); lmax[c] = -__builtin_inff(); }

#define MMA(v, B)                                                                         \
    do {                                                                                  \
        lmin[B + 0] = fminf(lmin[B + 0], (v).x); lmax[B + 0] = fmaxf(lmax[B + 0], (v).x); \
        lmin[B + 1] = fminf(lmin[B + 1], (v).y); lmax[B + 1] = fmaxf(lmax[B + 1], (v).y); \
        lmin[B + 2] = fminf(lmin[B + 2], (v).z); lmax[B + 2] = fmaxf(lmax[B + 2], (v).z); \
        lmin[B + 3] = fminf(lmin[B + 3], (v).w); lmax[B + 3] = fmaxf(lmax[B + 3], (v).w); \
    } while (0)

    // NTH_A even -> all of this thread's quads share parity -> one column group.
    if (((gid << 2) & 7) == 0) {
        if (h0) MMA(fv0, 0);
        if (h1) MMA(fv1, 0);
        if (h2) MMA(fv2, 0);
        if (h3) MMA(fv3, 0);
        for (int q = gid + 4 * NTH_A; q < n4; q += NTH_A) { float4 v = f4[q]; MMA(v, 0); }
    } else {
        if (h0) MMA(fv0, 4);
        if (h1) MMA(fv1, 4);
        if (h2) MMA(fv2, 4);
        if (h3) MMA(fv3, 4);
        for (int q = gid + 4 * NTH_A; q < n4; q += NTH_A) { float4 v = f4[q]; MMA(v, 4); }
    }
#undef MMA

    // generic scalar tail (n % 4 != 0) — static-index via unrolled predicate
    for (int i = (n4 << 2) + gid; i < n; i += NTH_A) {
        float v = feats[i];
        int c = i & 7;
#pragma unroll
        for (int cc = 0; cc < NV; ++cc)
            if (cc == c) { lmin[cc] = fminf(lmin[cc], v); lmax[cc] = fmaxf(lmax[cc], v); }
    }

    // 64-lane wave butterfly per column
#pragma unroll
    for (int c = 0; c < NV; ++c) {
        float mn = lmin[c], mx = lmax[c];
#pragma unroll
        for (int m = 32; m >= 1; m >>= 1) {
            mn = fminf(mn, __shfl_xor(mn, m));
            mx = fmaxf(mx, __shfl_xor(mx, m));
        }
        lmin[c] = mn; lmax[c] = mx;
    }
    __shared__ float smin[4][NV], smax[4][NV];
    const int wave = tid >> 6, lane = tid & 63;
    if (lane == 0) {
#pragma unroll
        for (int c = 0; c < NV; ++c) { smin[wave][c] = lmin[c]; smax[wave][c] = lmax[c]; }
    }
    __syncthreads();
    if (tid < NV) {
        float mn = fminf(fminf(smin[0][tid], smin[1][tid]), fminf(smin[2][tid], smin[3][tid]));
        float mx = fmaxf(fmaxf(smax[0][tid], smax[1][tid]), fmaxf(smax[2][tid], smax[3][tid]));
        ws[bid * NV + tid] = mn;
        ws[GRID_A * NV + bid * NV + tid] = mx;
    }
}

// Per-quad processing: 4 consecutive elements = 4 consecutive columns
// (quad parity fixed). Exact reference bin rule preserved:
// candidate via rstep, then monotone fix-up against rint((lin_b - feat)*1e6).
__device__ __forceinline__ void proc4(float4 fvq, int q, const float* __restrict__ slin,
                                      const float* __restrict__ sfmin,
                                      const float* __restrict__ sstep,
                                      const float* __restrict__ srstep,
                                      float* __restrict__ out, int n) {
    const int v0 = (q << 2) & 7;  // 0 or 4
    const int i0 = q << 2;
    float fe[4] = {fvq.x, fvq.y, fvq.z, fvq.w};
    float bins[4], regs[4];
#pragma unroll
    for (int j = 0; j < 4; ++j) {
        const int v = v0 + j;
        const float* lv = &slin[v * 129];
        const float feat = fe[j];
        const float fmn = sfmin[v];
        const float step = sstep[v];
        const float rstep = srstep[v];
        int b = (int)floorf(__fmul_rn(__fsub_rn(feat, fmn), rstep));
        b = b < 0 ? 0 : (b > 127 ? 127 : b);
        while (b < NBINS - 1 &&
               rintf(__fmul_rn(__fsub_rn(lv[b + 1], feat), 1.0e6f)) <= 0.0f) ++b;
        while (b > 0 &&
               rintf(__fmul_rn(__fsub_rn(lv[b], feat), 1.0e6f)) > 0.0f) --b;
        const float val = lv[b];
        bins[j] = (float)b;
        regs[j] = __fdiv_rn(fmaxf(__fsub_rn(feat, val), 0.0f), step);
    }
    *(float4*)(out + i0) = make_float4(bins[0], bins[1], bins[2], bins[3]);
    if ((n & 3) == 0) {  // out+n is 16B-aligned iff n%4==0
        *(float4*)(out + n + i0) = make_float4(regs[0], regs[1], regs[2], regs[3]);
    } else {
        out[n + i0 + 0] = regs[0]; out[n + i0 + 1] = regs[1];
        out[n + i0 + 2] = regs[2]; out[n + i0 + 3] = regs[3];
    }
}

// One quad per thread. The quad load is issued BEFORE the combine/lin
// preamble so its HBM latency hides under that work; all I/O is float4.
__global__ __launch_bounds__(BLK_Q) void k_quantize2(const float* __restrict__ feats,
                                                     const float* __restrict__ ws,
                                                     float* __restrict__ out, int n) {
    __shared__ float cmin[4][NV], cmax[4][NV];
    __shared__ float sgmin[NV], sgmax[NV];
    __shared__ float slin[NV * 129];  // +1 pad: bank = (129v+b)%32 = (v+b)%32
    __shared__ float sfmin[NV], sstep[NV], srstep[NV];
    const int tid = threadIdx.x;
    const int gid = blockIdx.x * BLK_Q + tid;
    const int nth = gridDim.x * BLK_Q;
    const int n4 = n >> 2;
    const float4* f4 = (const float4*)feats;
    const int wave = tid >> 6, lane = tid & 63;

    // ---- prefetch this thread's quad NOW ----
    const bool h0 = gid < n4;
    float4 fv0;
    if (h0) fv0 = f4[gid];

    // ---- all 4 waves combine the 256 partials (64 per wave) ----
    {
        const int pb = (wave << 6) | lane;  // partial row for this lane
        const float4* w4 = (const float4*)ws;
        float4 a  = w4[2 * pb];
        float4 b4 = w4[2 * pb + 1];
        float4 c4 = w4[2 * GRID_A + 2 * pb];
        float4 d4 = w4[2 * GRID_A + 2 * pb + 1];
        float mn[NV] = {a.x, a.y, a.z, a.w, b4.x, b4.y, b4.z, b4.w};
        float mx[NV] = {c4.x, c4.y, c4.z, c4.w, d4.x, d4.y, d4.z, d4.w};
#pragma unroll
        for (int c = 0; c < NV; ++c) {
#pragma unroll
            for (int m = 32; m >= 1; m >>= 1) {
                mn[c] = fminf(mn[c], __shfl_xor(mn[c], m));
                mx[c] = fmaxf(mx[c], __shfl_xor(mx[c], m));
            }
        }
        if (lane == 0) {
#pragma unroll
            for (int c = 0; c < NV; ++c) { cmin[wave][c] = mn[c]; cmax[wave][c] = mx[c]; }
        }
    }
    __syncthreads();
    if (tid < NV) {
        sgmin[tid] = fminf(fminf(cmin[0][tid], cmin[1][tid]), fminf(cmin[2][tid], cmin[3][tid]));
        sgmax[tid] = fmaxf(fmaxf(cmax[0][tid], cmax[1][tid]), fmaxf(cmax[2][tid], cmax[3][tid]));
    }
    __syncthreads();

    // ---- lin table (exact reference arithmetic: mul then add, no FMA) ----
    for (int e = tid; e < NV * NBINS; e += BLK_Q) {
        int v = e >> 7;
        int b = e & 127;
        float fmn = sgmin[v];
        float range = __fsub_rn(sgmax[v], fmn);        // (fmax - fmin), f32
        float tb = __fdiv_rn((float)b, 127.0f);        // t[b] = b/127, f32
        slin[v * 129 + b] = __fadd_rn(fmn, __fmul_rn(range, tb));
    }
    __syncthreads();
    if (tid < NV) {
        float s0 = slin[tid * 129 + 0];
        float s1 = slin[tid * 129 + 1];
        sfmin[tid] = s0;
        float st = __fsub_rn(s1, s0);
        sstep[tid] = st;
        srstep[tid] = __fdiv_rn(1.0f, st);  // candidate-only; fixups make bin exact
    }
    __syncthreads();

    // ---- quantize the prefetched quad; safety strides are normally empty ----
    if (h0) proc4(fv0, gid, slin, sfmin, sstep, srstep, out, n);
    for (int q = gid + nth; q < n4; q += nth)
        proc4(f4[q], q, slin, sfmin, sstep, srstep, out, n);

    // scalar tail (n % 4 != 0)
    for (int i = (n4 << 2) + gid; i < n; i += nth) {
        const int v = i & 7;
        const float feat = feats[i];
        const float* lv = &slin[v * 129];
        const float fmn = sfmin[v];
        const float step = sstep[v];
        int b = (int)floorf(__fmul_rn(__fsub_rn(feat, fmn), srstep[v]));
        b = b < 0 ? 0 : (b > 127 ? 127 : b);
        while (b < NBINS - 1 &&
               rintf(__fmul_rn(__fsub_rn(lv[b + 1], feat), 1.0e6f)) <= 0.0f) ++b;
        while (b > 0 &&
               rintf(__fmul_rn(__fsub_rn(lv[b], feat), 1.0e6f)) > 0.0f) --b;
        out[i] = (float)b;
        out[n + i] = __fdiv_rn(fmaxf(__fsub_rn(feat, lv[b]), 0.0f), step);
    }
}

extern "C" void kernel_launch(void* const* d_in, const int* in_sizes, int n_in,
                              void* d_out, int out_size, void* d_ws, size_t ws_size,
                              hipStream_t stream) {
    const float* feats = (const float*)d_in[0];
    float* ws = (float*)d_ws;
    float* out = (float*)d_out;
    const int n = in_sizes[0];  // 100000 * 8 flat
    const int n4 = n >> 2;
    int grid_q = (n4 + BLK_Q - 1) / BLK_Q;
    if (grid_q < 1) grid_q = 1;
    k_colminmax<<<GRID_A, BLK_A, 0, stream>>>(feats, ws, n);
    k_quantize2<<<grid_q, BLK_Q, 0, stream>>>(feats, ws, out, n);
}